// Round 1
// baseline (11738.116 us; speedup 1.0000x reference)
//
#include <hip/hip_runtime.h>
#include <math.h>

// ---------------- problem constants ----------------
#define BB 16
#define NBOX 588          // A * 14 * 14
#define TOPJ 392          // J
#define TOPK 196          // K
#define EMBED 768

// ---------------- generic direct conv (NCHW) ----------------
template<int KH, int KW, int STRIDE, int PAD, int TX>
__global__ void conv_direct(const float* __restrict__ in, const float* __restrict__ wgt,
                            const float* __restrict__ bias, float* __restrict__ out,
                            int Cin, int Hin, int Win, int Cout, int Hout, int Wout) {
    int wq = (Wout + TX - 1) / TX;
    long idx = (long)blockIdx.x * blockDim.x + threadIdx.x;
    long total = (long)BB * Cout * Hout * wq;
    if (idx >= total) return;
    int qx = (int)(idx % wq);
    long t = idx / wq;
    int oy = (int)(t % Hout); t /= Hout;
    int oc = (int)(t % Cout);
    int b  = (int)(t / Cout);
    int ox0 = qx * TX;

    float acc[TX];
    float bv = bias[oc];
#pragma unroll
    for (int u = 0; u < TX; ++u) acc[u] = bv;

    const float* wb = wgt + (long)oc * Cin * KH * KW;
    const float* ib = in  + (long)b  * Cin * Hin * Win;
    for (int ic = 0; ic < Cin; ++ic) {
        const float* wc = wb + ic * KH * KW;
        const float* ip = ib + (long)ic * Hin * Win;
#pragma unroll
        for (int ky = 0; ky < KH; ++ky) {
            int iy = oy * STRIDE - PAD + ky;
            if (iy < 0 || iy >= Hin) continue;
            const float* irow = ip + (long)iy * Win;
#pragma unroll
            for (int kx = 0; kx < KW; ++kx) {
                float wv = wc[ky * KW + kx];
#pragma unroll
                for (int u = 0; u < TX; ++u) {
                    int ox = ox0 + u;
                    int ix = ox * STRIDE - PAD + kx;
                    if (ox < Wout && ix >= 0 && ix < Win)
                        acc[u] = fmaf(irow[ix], wv, acc[u]);
                }
            }
        }
    }
    float* ob = out + (((long)(b * Cout + oc) * Hout) + oy) * Wout;
#pragma unroll
    for (int u = 0; u < TX; ++u)
        if (ox0 + u < Wout) ob[ox0 + u] = acc[u];
}

// ---------------- BN statistics (deterministic two-stage) ----------------
#define SPLIT 16
__global__ void bn_stats_partial(const float* __restrict__ x, float* __restrict__ psum,
                                 float* __restrict__ psq, int C, int HW) {
    int c    = blockIdx.x / SPLIT;
    int part = blockIdx.x % SPLIT;
    long total = (long)BB * HW;
    float s = 0.f, sq = 0.f;
    for (long t = (long)part * blockDim.x + threadIdx.x; t < total;
         t += (long)SPLIT * blockDim.x) {
        int b = (int)(t / HW);
        int i = (int)(t % HW);
        float v = x[((long)(b * C + c)) * HW + i];
        s += v; sq += v * v;
    }
    for (int o = 32; o > 0; o >>= 1) { s += __shfl_down(s, o); sq += __shfl_down(sq, o); }
    __shared__ float rs[4], rq[4];
    int tid = threadIdx.x;
    if ((tid & 63) == 0) { rs[tid >> 6] = s; rq[tid >> 6] = sq; }
    __syncthreads();
    if (tid == 0) {
        psum[c * SPLIT + part] = rs[0] + rs[1] + rs[2] + rs[3];
        psq [c * SPLIT + part] = rq[0] + rq[1] + rq[2] + rq[3];
    }
}

__global__ void bn_stats_final(const float* __restrict__ psum, const float* __restrict__ psq,
                               float* __restrict__ st, int C) {
    int c = blockIdx.x * blockDim.x + threadIdx.x;
    if (c >= C) return;
    float s = 0.f, q = 0.f;
    for (int p = 0; p < SPLIT; ++p) { s += psum[c * SPLIT + p]; q += psq[c * SPLIT + p]; }
    st[c] = s; st[C + c] = q;
}

__global__ void bn_relu(float* __restrict__ x, const float* __restrict__ st,
                        const float* __restrict__ gamma, const float* __restrict__ beta,
                        int C, int HW, long total, float inv_cnt) {
    long idx = (long)blockIdx.x * blockDim.x + threadIdx.x;
    if (idx >= total) return;
    int c = (int)((idx / HW) % C);
    float mean = st[c] * inv_cnt;
    float var  = st[C + c] * inv_cnt - mean * mean;
    float sc = gamma[c] * rsqrtf(var + 1e-5f);
    float v = (x[idx] - mean) * sc + beta[c];
    x[idx] = v > 0.f ? v : 0.f;
}

// ---------------- patch conv3 (2x2 s2) with NHWC output ----------------
// in: (B,128,28,28) NCHW ; w: (768,128,2,2) ; out: (B,14,14,768)
__global__ void patch3_nhwc(const float* __restrict__ in, const float* __restrict__ wgt,
                            const float* __restrict__ bias, float* __restrict__ out) {
    int by = blockIdx.x;            // b*14 + y
    int b = by / 14;
    int y = by % 14;
    __shared__ float iv[14 * 512];  // [x][ic*4 + dy*2 + dx]
    for (int t = threadIdx.x; t < 14 * 512; t += blockDim.x) {
        int x  = t / 512;
        int r  = t % 512;
        int ic = r >> 2;
        int dy = (r >> 1) & 1;
        int dx = r & 1;
        iv[t] = in[((long)(b * 128 + ic) * 28 + (2 * y + dy)) * 28 + (2 * x + dx)];
    }
    __syncthreads();
    for (int c = threadIdx.x; c < EMBED; c += blockDim.x) {
        const float4* wc = reinterpret_cast<const float4*>(wgt + (long)c * 512);
        float acc[14];
        float bv = bias[c];
#pragma unroll
        for (int x = 0; x < 14; ++x) acc[x] = bv;
        const float4* ivv = reinterpret_cast<const float4*>(iv);
        for (int t = 0; t < 128; ++t) {
            float4 wv = wc[t];
#pragma unroll
            for (int x = 0; x < 14; ++x) {
                float4 v = ivv[x * 128 + t];
                acc[x] += wv.x * v.x + wv.y * v.y + wv.z * v.z + wv.w * v.w;
            }
        }
        for (int x = 0; x < 14; ++x)
            out[(((long)(b * 14 + y) * 14) + x) * EMBED + c] = acc[x];
    }
}

// ---------------- top-K selection (stable ascending rank) + softmax gate ----------------
__global__ void topk_kernel(const float* __restrict__ score, int* __restrict__ sel,
                            float* __restrict__ gate) {
    int b = blockIdx.x;
    int tid = threadIdx.x;
    __shared__ float s[NBOX];
    __shared__ float red[4];
    for (int n = tid; n < NBOX; n += blockDim.x) s[n] = score[b * NBOX + n];
    __syncthreads();

    // max
    float mx = -3.0e38f;
    for (int n = tid; n < NBOX; n += blockDim.x) mx = fmaxf(mx, s[n]);
    for (int o = 32; o > 0; o >>= 1) mx = fmaxf(mx, __shfl_down(mx, o));
    if ((tid & 63) == 0) red[tid >> 6] = mx;
    __syncthreads();
    mx = fmaxf(fmaxf(red[0], red[1]), fmaxf(red[2], red[3]));
    __syncthreads();

    // sum of exp
    float se = 0.f;
    for (int n = tid; n < NBOX; n += blockDim.x) se += expf(s[n] - mx);
    for (int o = 32; o > 0; o >>= 1) se += __shfl_down(se, o);
    if ((tid & 63) == 0) red[tid >> 6] = se;
    __syncthreads();
    se = red[0] + red[1] + red[2] + red[3];

    // stable ascending rank; selected iff rank >= J
    for (int n = tid; n < NBOX; n += blockDim.x) {
        float v = s[n];
        int rank = 0;
        for (int m = 0; m < NBOX; ++m) {
            float u = s[m];
            rank += (u < v) || (u == v && m < n);
        }
        if (rank >= TOPJ) {
            int k = rank - TOPJ;
            float p = expf(v - mx) / se;
            sel [b * TOPK + k] = n;
            gate[b * TOPK + k] = (1.0f - p) + p;   // matches (onehot - sm) + sm forward
        }
    }
}

// ---------------- ROI align 1x1 + gate ----------------
// e3: (B,14,14,768) NHWC
__global__ void roi_gather(const float* __restrict__ e3, const int* __restrict__ sel,
                           const float* __restrict__ gate, float* __restrict__ out) {
    int bk = blockIdx.x;                 // b*196 + k
    int b = bk / TOPK;
    int n = sel[bk];
    float gt = gate[bk];
    int a   = n / 196;
    int pos = n % 196;
    int i = pos / 14;
    int j = pos % 14;
    int S = a + 1;
    float inv_cnt = 1.0f / (float)(S * S);

    __shared__ int   cidx[9][4];
    __shared__ float cw  [9][4];
    if (threadIdx.x == 0) {
        int t = 0;
        for (int p = 0; p < S; ++p) {
            // row coordinate comes from j (box "by1" = cx - w/2)
            float yy = (float)j - S * 0.5f + p + 0.5f;
            float yc = fmaxf(yy, 0.0f);
            int yf = (int)floorf(yc);
            int y_lo, y_hi; float ly;
            if (yf >= 13) { y_lo = 13; y_hi = 13; ly = 0.f; }
            else          { y_lo = yf; y_hi = yf + 1; ly = yc - (float)yf; }
            for (int q = 0; q < S; ++q) {
                // col coordinate comes from i
                float xx = (float)i - S * 0.5f + q + 0.5f;
                float xc = fmaxf(xx, 0.0f);
                int xf = (int)floorf(xc);
                int x_lo, x_hi; float lx;
                if (xf >= 13) { x_lo = 13; x_hi = 13; lx = 0.f; }
                else          { x_lo = xf; x_hi = xf + 1; lx = xc - (float)xf; }
                cidx[t][0] = y_lo * 14 + x_lo;  cw[t][0] = (1.f - ly) * (1.f - lx);
                cidx[t][1] = y_lo * 14 + x_hi;  cw[t][1] = (1.f - ly) * lx;
                cidx[t][2] = y_hi * 14 + x_lo;  cw[t][2] = ly * (1.f - lx);
                cidx[t][3] = y_hi * 14 + x_hi;  cw[t][3] = ly * lx;
                ++t;
            }
        }
    }
    __syncthreads();
    int NS = S * S;
    const float* base = e3 + (long)b * 196 * EMBED;
    for (int c = threadIdx.x; c < EMBED; c += blockDim.x) {
        float acc = 0.f;
        for (int t = 0; t < NS; ++t) {
            acc += cw[t][0] * base[cidx[t][0] * EMBED + c]
                 + cw[t][1] * base[cidx[t][1] * EMBED + c]
                 + cw[t][2] * base[cidx[t][2] * EMBED + c]
                 + cw[t][3] * base[cidx[t][3] * EMBED + c];
        }
        out[(long)bk * EMBED + c] = acc * inv_cnt * gt;
    }
}

// ---------------- host launch ----------------
extern "C" void kernel_launch(void* const* d_in, const int* in_sizes, int n_in,
                              void* d_out, int out_size, void* d_ws, size_t ws_size,
                              hipStream_t stream) {
    const float* x   = (const float*)d_in[0];
    const float* pw1 = (const float*)d_in[1];
    const float* pb1 = (const float*)d_in[2];
    const float* pw2 = (const float*)d_in[3];
    const float* pb2 = (const float*)d_in[4];
    const float* pw3 = (const float*)d_in[5];
    const float* pb3 = (const float*)d_in[6];
    const float* rw1 = (const float*)d_in[7];
    const float* rb1 = (const float*)d_in[8];
    const float* g1  = (const float*)d_in[9];
    const float* b1  = (const float*)d_in[10];
    const float* rw2 = (const float*)d_in[11];
    const float* rb2 = (const float*)d_in[12];
    const float* g2  = (const float*)d_in[13];
    const float* b2  = (const float*)d_in[14];
    const float* rw3 = (const float*)d_in[15];
    const float* rb3 = (const float*)d_in[16];
    const float* g3  = (const float*)d_in[17];
    const float* b3  = (const float*)d_in[18];
    const float* rw4 = (const float*)d_in[19];
    const float* rb4 = (const float*)d_in[20];

    float* ws = (float*)d_ws;
    // region A: r1 (16,64,112,112), later e3 NHWC (16,14,14,768)
    const long SZ_A = 16L * 64 * 112 * 112;       // 12,845,056
    // region B: r2 (16,128,56,56), later e1 (16,64,56,56)
    const long SZ_B = 16L * 128 * 56 * 56;        // 6,422,528
    // region C: r3 (16,256,28,28), later e2 (16,128,28,28)
    const long SZ_C = 16L * 256 * 28 * 28;        // 3,211,264
    const long OFF_A = 0;
    const long OFF_B = OFF_A + SZ_A;
    const long OFF_C = OFF_B + SZ_B;
    const long OFF_SCORE = OFF_C + SZ_C;          // 16*588
    const long OFF_PS = OFF_SCORE + 16L * NBOX;
    const long OFF_PQ = OFF_PS + 256L * SPLIT;
    const long OFF_ST = OFF_PQ + 256L * SPLIT;
    const long OFF_GATE = OFF_ST + 1024;
    const long OFF_SEL  = OFF_GATE + 16L * TOPK;

    float* r1 = ws + OFF_A;
    float* r2 = ws + OFF_B;
    float* r3 = ws + OFF_C;
    float* e3 = ws + OFF_A;
    float* e1 = ws + OFF_B;
    float* e2 = ws + OFF_C;
    float* score = ws + OFF_SCORE;
    float* psum  = ws + OFF_PS;
    float* psq   = ws + OFF_PQ;
    float* st    = ws + OFF_ST;
    float* gate  = ws + OFF_GATE;
    int*   sel   = (int*)(ws + OFF_SEL);

    const int T = 256;

    // ---- region-proposal path (fp32 throughout: score ordering must be exact) ----
    // rp1: (16,3,224,224) -> (16,64,112,112)
    {
        long total = 16L * 64 * 112 * 28;  // TX=4 -> 28 quads
        conv_direct<3,3,2,1,4><<<(int)((total + T - 1) / T), T, 0, stream>>>(
            x, rw1, rb1, r1, 3, 224, 224, 64, 112, 112);
        bn_stats_partial<<<64 * SPLIT, T, 0, stream>>>(r1, psum, psq, 64, 112 * 112);
        bn_stats_final<<<1, T, 0, stream>>>(psum, psq, st, 64);
        long tot = 16L * 64 * 112 * 112;
        bn_relu<<<(int)((tot + T - 1) / T), T, 0, stream>>>(
            r1, st, g1, b1, 64, 112 * 112, tot, 1.0f / (16.f * 112 * 112));
    }
    // rp2: -> (16,128,56,56)
    {
        long total = 16L * 128 * 56 * 14;
        conv_direct<3,3,2,1,4><<<(int)((total + T - 1) / T), T, 0, stream>>>(
            r1, rw2, rb2, r2, 64, 112, 112, 128, 56, 56);
        bn_stats_partial<<<128 * SPLIT, T, 0, stream>>>(r2, psum, psq, 128, 56 * 56);
        bn_stats_final<<<1, T, 0, stream>>>(psum, psq, st, 128);
        long tot = 16L * 128 * 56 * 56;
        bn_relu<<<(int)((tot + T - 1) / T), T, 0, stream>>>(
            r2, st, g2, b2, 128, 56 * 56, tot, 1.0f / (16.f * 56 * 56));
    }
    // rp3: -> (16,256,28,28)
    {
        long total = 16L * 256 * 28 * 7;
        conv_direct<3,3,2,1,4><<<(int)((total + T - 1) / T), T, 0, stream>>>(
            r2, rw3, rb3, r3, 128, 56, 56, 256, 28, 28);
        bn_stats_partial<<<256 * SPLIT, T, 0, stream>>>(r3, psum, psq, 256, 28 * 28);
        bn_stats_final<<<1, T, 0, stream>>>(psum, psq, st, 256);
        long tot = 16L * 256 * 28 * 28;
        bn_relu<<<(int)((tot + T - 1) / T), T, 0, stream>>>(
            r3, st, g3, b3, 256, 28 * 28, tot, 1.0f / (16.f * 28 * 28));
    }
    // rp4 (score): -> (16,3,14,14)
    {
        long total = 16L * 3 * 14 * 4;
        conv_direct<3,3,2,1,4><<<(int)((total + T - 1) / T), T, 0, stream>>>(
            r3, rw4, rb4, score, 256, 28, 28, 3, 14, 14);
    }
    // top-K + gate
    topk_kernel<<<16, T, 0, stream>>>(score, sel, gate);

    // ---- patch-embed path ----
    // patch1: (16,3,224,224) -> (16,64,56,56)   [region B free after rp3]
    {
        long total = 16L * 64 * 56 * 14;
        conv_direct<4,4,4,0,4><<<(int)((total + T - 1) / T), T, 0, stream>>>(
            x, pw1, pb1, e1, 3, 224, 224, 64, 56, 56);
    }
    // patch2: -> (16,128,28,28)                 [region C free after rp4]
    {
        long total = 16L * 128 * 28 * 7;
        conv_direct<2,2,2,0,4><<<(int)((total + T - 1) / T), T, 0, stream>>>(
            e1, pw2, pb2, e2, 64, 56, 56, 128, 28, 28);
    }
    // patch3: -> (16,14,14,768) NHWC            [region A free after rp2]
    patch3_nhwc<<<16 * 14, T, 0, stream>>>(e2, pw3, pb3, e3);

    // ---- ROI align + gate -> d_out (16,196,768) ----
    roi_gather<<<16 * TOPK, T, 0, stream>>>(e3, sel, gate, (float*)d_out);
}

// Round 2
// 713.335 us; speedup vs baseline: 16.4553x; 16.4553x over previous
//
#include <hip/hip_runtime.h>
#include <math.h>

// ---------------- problem constants ----------------
#define BB 16
#define NBOX 588          // A * 14 * 14
#define TOPJ 392          // J
#define TOPK 196          // K
#define EMBED 768

// ---------------- weight transpose: [Cout][Kin] -> [Kin][Cout] ----------------
__global__ void w_transpose(const float* __restrict__ w, float* __restrict__ wT,
                            int Cout, int Kin) {
    int idx = blockIdx.x * 256 + threadIdx.x;
    if (idx >= Cout * Kin) return;
    int oc = idx % Cout;
    int k  = idx / Cout;
    wT[(long)k * Cout + oc] = w[(long)oc * Kin + k];
}

// ---------------- register-blocked implicit-GEMM conv ----------------
// lane -> contiguous flattened (b,oy,ox); OCT output channels per thread.
// wT layout: [(ic*KH+ky)*KW+kx][Cout] so the OCT weights per tap are one
// wave-uniform contiguous scalar load. gridDim.z = ic-splits (partials are
// written at out + z*B*HW*Cout; z==0 carries the bias).
template<int KH, int KW, int S, int P, int OCT, bool NHWC>
__global__ __launch_bounds__(256) void conv_t(
    const float* __restrict__ in, const float* __restrict__ wT,
    const float* __restrict__ bias, float* __restrict__ out,
    int Cin, int Hin, int Win, int Cout, int Hout, int Wout)
{
    const int  hw    = Hout * Wout;
    const long total = (long)BB * hw;
    long sp = (long)blockIdx.x * 256 + threadIdx.x;
    if (sp >= total) return;
    int b  = (int)(sp / hw);
    int r  = (int)(sp - (long)b * hw);
    int oy = r / Wout;
    int ox = r - oy * Wout;
    int oc0 = blockIdx.y * OCT;

    int icchunk = Cin / gridDim.z;
    int ic0 = blockIdx.z * icchunk;

    float acc[OCT];
    if (blockIdx.z == 0) {
#pragma unroll
        for (int i = 0; i < OCT; ++i) acc[i] = bias[oc0 + i];
    } else {
#pragma unroll
        for (int i = 0; i < OCT; ++i) acc[i] = 0.f;
    }

    // precompute clamped tap coords + validity masks
    int  ixc[KW];
    long yoff[KH];
    float xm[KW], ym[KH];
#pragma unroll
    for (int kx = 0; kx < KW; ++kx) {
        int ix = ox * S - P + kx;
        xm[kx] = (ix >= 0 && ix < Win) ? 1.f : 0.f;
        ixc[kx] = min(max(ix, 0), Win - 1);
    }
#pragma unroll
    for (int ky = 0; ky < KH; ++ky) {
        int iy = oy * S - P + ky;
        ym[ky] = (iy >= 0 && iy < Hin) ? 1.f : 0.f;
        yoff[ky] = (long)min(max(iy, 0), Hin - 1) * Win;
    }
    float m[KH][KW];
#pragma unroll
    for (int ky = 0; ky < KH; ++ky)
#pragma unroll
        for (int kx = 0; kx < KW; ++kx) m[ky][kx] = ym[ky] * xm[kx];

    const float* ib = in + ((long)b * Cin) * Hin * Win;
    for (int ic = ic0; ic < ic0 + icchunk; ++ic) {
        const float* ip = ib + (long)ic * Hin * Win;
#pragma unroll
        for (int ky = 0; ky < KH; ++ky) {
            const float* row = ip + yoff[ky];
#pragma unroll
            for (int kx = 0; kx < KW; ++kx) {
                float v = row[ixc[kx]];
                if (P > 0) v *= m[ky][kx];
                const float* wr = wT + ((long)((ic * KH + ky) * KW + kx)) * Cout + oc0;
#pragma unroll
                for (int i = 0; i < OCT; ++i) acc[i] = fmaf(v, wr[i], acc[i]);
            }
        }
    }

    float* obase = out + (long)blockIdx.z * (total * Cout);
    if (NHWC) {
        float* ob = obase + sp * Cout + oc0;
#pragma unroll
        for (int i = 0; i < OCT; ++i) ob[i] = acc[i];
    } else {
        float* ob = obase + ((long)b * Cout + oc0) * hw + r;
#pragma unroll
        for (int i = 0; i < OCT; ++i) ob[(long)i * hw] = acc[i];
    }
}

// ---------------- deterministic partial-sum reduce (rp4 split-K) ----------------
__global__ void reduce_parts(const float* __restrict__ part, float* __restrict__ out,
                             long n, int nz, long stride) {
    long i = (long)blockIdx.x * 256 + threadIdx.x;
    if (i >= n) return;
    float s = 0.f;
    for (int z = 0; z < nz; ++z) s += part[(long)z * stride + i];
    out[i] = s;
}

// ---------------- BN statistics (deterministic two-stage) ----------------
#define SPLIT 16
__global__ void bn_stats_partial(const float* __restrict__ x, float* __restrict__ psum,
                                 float* __restrict__ psq, int C, int HW) {
    int c    = blockIdx.x / SPLIT;
    int part = blockIdx.x % SPLIT;
    long total = (long)BB * HW;
    float s = 0.f, sq = 0.f;
    for (long t = (long)part * blockDim.x + threadIdx.x; t < total;
         t += (long)SPLIT * blockDim.x) {
        int b = (int)(t / HW);
        int i = (int)(t % HW);
        float v = x[((long)(b * C + c)) * HW + i];
        s += v; sq += v * v;
    }
    for (int o = 32; o > 0; o >>= 1) { s += __shfl_down(s, o); sq += __shfl_down(sq, o); }
    __shared__ float rs[4], rq[4];
    int tid = threadIdx.x;
    if ((tid & 63) == 0) { rs[tid >> 6] = s; rq[tid >> 6] = sq; }
    __syncthreads();
    if (tid == 0) {
        psum[c * SPLIT + part] = rs[0] + rs[1] + rs[2] + rs[3];
        psq [c * SPLIT + part] = rq[0] + rq[1] + rq[2] + rq[3];
    }
}

__global__ void bn_stats_final(const float* __restrict__ psum, const float* __restrict__ psq,
                               float* __restrict__ st, int C) {
    int c = blockIdx.x * blockDim.x + threadIdx.x;
    if (c >= C) return;
    float s = 0.f, q = 0.f;
    for (int p = 0; p < SPLIT; ++p) { s += psum[c * SPLIT + p]; q += psq[c * SPLIT + p]; }
    st[c] = s; st[C + c] = q;
}

__global__ void bn_relu(float* __restrict__ x, const float* __restrict__ st,
                        const float* __restrict__ gamma, const float* __restrict__ beta,
                        int C, int HW, long total, float inv_cnt) {
    long idx = (long)blockIdx.x * blockDim.x + threadIdx.x;
    if (idx >= total) return;
    int c = (int)((idx / HW) % C);
    float mean = st[c] * inv_cnt;
    float var  = st[C + c] * inv_cnt - mean * mean;
    float sc = gamma[c] * rsqrtf(var + 1e-5f);
    float v = (x[idx] - mean) * sc + beta[c];
    x[idx] = v > 0.f ? v : 0.f;
}

// ---------------- top-K selection (stable ascending rank) + softmax gate ----------------
__global__ void topk_kernel(const float* __restrict__ score, int* __restrict__ sel,
                            float* __restrict__ gate) {
    int b = blockIdx.x;
    int tid = threadIdx.x;
    __shared__ float s[NBOX];
    __shared__ float red[4];
    for (int n = tid; n < NBOX; n += blockDim.x) s[n] = score[b * NBOX + n];
    __syncthreads();

    float mx = -3.0e38f;
    for (int n = tid; n < NBOX; n += blockDim.x) mx = fmaxf(mx, s[n]);
    for (int o = 32; o > 0; o >>= 1) mx = fmaxf(mx, __shfl_down(mx, o));
    if ((tid & 63) == 0) red[tid >> 6] = mx;
    __syncthreads();
    mx = fmaxf(fmaxf(red[0], red[1]), fmaxf(red[2], red[3]));
    __syncthreads();

    float se = 0.f;
    for (int n = tid; n < NBOX; n += blockDim.x) se += expf(s[n] - mx);
    for (int o = 32; o > 0; o >>= 1) se += __shfl_down(se, o);
    if ((tid & 63) == 0) red[tid >> 6] = se;
    __syncthreads();
    se = red[0] + red[1] + red[2] + red[3];

    for (int n = tid; n < NBOX; n += blockDim.x) {
        float v = s[n];
        int rank = 0;
        for (int m = 0; m < NBOX; ++m) {
            float u = s[m];
            rank += (u < v) || (u == v && m < n);
        }
        if (rank >= TOPJ) {
            int k = rank - TOPJ;
            float p = expf(v - mx) / se;
            sel [b * TOPK + k] = n;
            gate[b * TOPK + k] = (1.0f - p) + p;   // matches (onehot - sm) + sm forward
        }
    }
}

// ---------------- ROI align 1x1 + gate (e3 is NHWC) ----------------
__global__ void roi_gather(const float* __restrict__ e3, const int* __restrict__ sel,
                           const float* __restrict__ gate, float* __restrict__ out) {
    int bk = blockIdx.x;                 // b*196 + k
    int b = bk / TOPK;
    int n = sel[bk];
    float gt = gate[bk];
    int a   = n / 196;
    int pos = n % 196;
    int i = pos / 14;
    int j = pos % 14;
    int S = a + 1;
    float inv_cnt = 1.0f / (float)(S * S);

    __shared__ int   cidx[9][4];
    __shared__ float cw  [9][4];
    if (threadIdx.x == 0) {
        int t = 0;
        for (int p = 0; p < S; ++p) {
            float yy = (float)j - S * 0.5f + p + 0.5f;   // row coord from j
            float yc = fmaxf(yy, 0.0f);
            int yf = (int)floorf(yc);
            int y_lo, y_hi; float ly;
            if (yf >= 13) { y_lo = 13; y_hi = 13; ly = 0.f; }
            else          { y_lo = yf; y_hi = yf + 1; ly = yc - (float)yf; }
            for (int q = 0; q < S; ++q) {
                float xx = (float)i - S * 0.5f + q + 0.5f;  // col coord from i
                float xc = fmaxf(xx, 0.0f);
                int xf = (int)floorf(xc);
                int x_lo, x_hi; float lx;
                if (xf >= 13) { x_lo = 13; x_hi = 13; lx = 0.f; }
                else          { x_lo = xf; x_hi = xf + 1; lx = xc - (float)xf; }
                cidx[t][0] = y_lo * 14 + x_lo;  cw[t][0] = (1.f - ly) * (1.f - lx);
                cidx[t][1] = y_lo * 14 + x_hi;  cw[t][1] = (1.f - ly) * lx;
                cidx[t][2] = y_hi * 14 + x_lo;  cw[t][2] = ly * (1.f - lx);
                cidx[t][3] = y_hi * 14 + x_hi;  cw[t][3] = ly * lx;
                ++t;
            }
        }
    }
    __syncthreads();
    int NS = S * S;
    const float* base = e3 + (long)b * 196 * EMBED;
    for (int c = threadIdx.x; c < EMBED; c += blockDim.x) {
        float acc = 0.f;
        for (int t = 0; t < NS; ++t) {
            acc += cw[t][0] * base[cidx[t][0] * EMBED + c]
                 + cw[t][1] * base[cidx[t][1] * EMBED + c]
                 + cw[t][2] * base[cidx[t][2] * EMBED + c]
                 + cw[t][3] * base[cidx[t][3] * EMBED + c];
        }
        out[(long)bk * EMBED + c] = acc * inv_cnt * gt;
    }
}

// ---------------- host launch ----------------
extern "C" void kernel_launch(void* const* d_in, const int* in_sizes, int n_in,
                              void* d_out, int out_size, void* d_ws, size_t ws_size,
                              hipStream_t stream) {
    const float* x   = (const float*)d_in[0];
    const float* pw1 = (const float*)d_in[1];
    const float* pb1 = (const float*)d_in[2];
    const float* pw2 = (const float*)d_in[3];
    const float* pb2 = (const float*)d_in[4];
    const float* pw3 = (const float*)d_in[5];
    const float* pb3 = (const float*)d_in[6];
    const float* rw1 = (const float*)d_in[7];
    const float* rb1 = (const float*)d_in[8];
    const float* g1  = (const float*)d_in[9];
    const float* b1  = (const float*)d_in[10];
    const float* rw2 = (const float*)d_in[11];
    const float* rb2 = (const float*)d_in[12];
    const float* g2  = (const float*)d_in[13];
    const float* b2  = (const float*)d_in[14];
    const float* rw3 = (const float*)d_in[15];
    const float* rb3 = (const float*)d_in[16];
    const float* g3  = (const float*)d_in[17];
    const float* b3  = (const float*)d_in[18];
    const float* rw4 = (const float*)d_in[19];
    const float* rb4 = (const float*)d_in[20];

    float* ws = (float*)d_ws;
    // region A: r1 (16,64,112,112), later e3 NHWC (16,14,14,768)
    const long SZ_A = 16L * 64 * 112 * 112;
    // region B: r2 (16,128,56,56), later rp4 partials, later e1 (16,64,56,56)
    const long SZ_B = 16L * 128 * 56 * 56;
    // region C: r3 (16,256,28,28), later e2 (16,128,28,28)
    const long SZ_C = 16L * 256 * 28 * 28;
    const long OFF_A = 0;
    const long OFF_B = OFF_A + SZ_A;
    const long OFF_C = OFF_B + SZ_B;
    const long OFF_SCORE = OFF_C + SZ_C;
    const long OFF_PS = OFF_SCORE + 16L * NBOX;
    const long OFF_PQ = OFF_PS + 256L * SPLIT;
    const long OFF_ST = OFF_PQ + 256L * SPLIT;
    const long OFF_GATE = OFF_ST + 1024;
    const long OFF_SEL  = OFF_GATE + 16L * TOPK;

    float* r1 = ws + OFF_A;
    float* r2 = ws + OFF_B;
    float* r3 = ws + OFF_C;
    float* e3 = ws + OFF_A;
    float* e1 = ws + OFF_B;
    float* e2 = ws + OFF_C;
    float* part4 = ws + OFF_B;            // rp4 split-K partials (B free after rp3)
    float* score = ws + OFF_SCORE;
    float* psum  = ws + OFF_PS;
    float* psq   = ws + OFF_PQ;
    float* st    = ws + OFF_ST;
    float* gate  = ws + OFF_GATE;
    int*   sel   = (int*)(ws + OFF_SEL);

    // transposed weights live in d_out (fully overwritten by roi_gather at the end)
    float* dout = (float*)d_out;
    float* t_rw1 = dout;                      // 64*27    = 1728
    float* t_rw2 = t_rw1 + 64L * 27;          // 128*576  = 73728
    float* t_rw3 = t_rw2 + 128L * 576;        // 256*1152 = 294912
    float* t_rw4 = t_rw3 + 256L * 1152;       // 3*2304   = 6912
    float* t_pw1 = t_rw4 + 3L * 2304;         // 64*48    = 3072
    float* t_pw2 = t_pw1 + 64L * 48;          // 128*256  = 32768
    float* t_pw3 = t_pw2 + 128L * 256;        // 768*512  = 393216  (end 806336 < 2408448)

    const int T = 256;
    auto tw = [&](const float* w, float* wT, int Cout, int Kin) {
        int n = Cout * Kin;
        w_transpose<<<(n + T - 1) / T, T, 0, stream>>>(w, wT, Cout, Kin);
    };
    tw(rw1, t_rw1, 64, 27);
    tw(rw2, t_rw2, 128, 576);
    tw(rw3, t_rw3, 256, 1152);
    tw(rw4, t_rw4, 3, 2304);
    tw(pw1, t_pw1, 64, 48);
    tw(pw2, t_pw2, 128, 256);
    tw(pw3, t_pw3, 768, 512);

    // ---- region-proposal path (fp32: argsort order must match) ----
    // rp1: (16,3,224,224) -> (16,64,112,112)
    conv_t<3,3,2,1,16,false><<<dim3(784, 4, 1), T, 0, stream>>>(
        x, t_rw1, rb1, r1, 3, 224, 224, 64, 112, 112);
    bn_stats_partial<<<64 * SPLIT, T, 0, stream>>>(r1, psum, psq, 64, 112 * 112);
    bn_stats_final<<<1, T, 0, stream>>>(psum, psq, st, 64);
    {
        long tot = 16L * 64 * 112 * 112;
        bn_relu<<<(int)((tot + T - 1) / T), T, 0, stream>>>(
            r1, st, g1, b1, 64, 112 * 112, tot, 1.0f / (16.f * 112 * 112));
    }
    // rp2: -> (16,128,56,56)
    conv_t<3,3,2,1,16,false><<<dim3(196, 8, 1), T, 0, stream>>>(
        r1, t_rw2, rb2, r2, 64, 112, 112, 128, 56, 56);
    bn_stats_partial<<<128 * SPLIT, T, 0, stream>>>(r2, psum, psq, 128, 56 * 56);
    bn_stats_final<<<1, T, 0, stream>>>(psum, psq, st, 128);
    {
        long tot = 16L * 128 * 56 * 56;
        bn_relu<<<(int)((tot + T - 1) / T), T, 0, stream>>>(
            r2, st, g2, b2, 128, 56 * 56, tot, 1.0f / (16.f * 56 * 56));
    }
    // rp3: -> (16,256,28,28)
    conv_t<3,3,2,1,16,false><<<dim3(49, 16, 1), T, 0, stream>>>(
        r2, t_rw3, rb3, r3, 128, 56, 56, 256, 28, 28);
    bn_stats_partial<<<256 * SPLIT, T, 0, stream>>>(r3, psum, psq, 256, 28 * 28);
    bn_stats_final<<<1, T, 0, stream>>>(psum, psq, st, 256);
    {
        long tot = 16L * 256 * 28 * 28;
        bn_relu<<<(int)((tot + T - 1) / T), T, 0, stream>>>(
            r3, st, g3, b3, 256, 28 * 28, tot, 1.0f / (16.f * 28 * 28));
    }
    // rp4 (score): -> (16,3,14,14), split-K over 8 ic-chunks, partials in region B
    conv_t<3,3,2,1,3,false><<<dim3(13, 1, 8), T, 0, stream>>>(
        r3, t_rw4, rb4, part4, 256, 28, 28, 3, 14, 14);
    reduce_parts<<<(9408 + T - 1) / T, T, 0, stream>>>(part4, score, 9408, 8, 9408);

    // top-K + gate
    topk_kernel<<<16, T, 0, stream>>>(score, sel, gate);

    // ---- patch-embed path ----
    // patch1: (16,3,224,224) -> (16,64,56,56)  [region B free: partials consumed]
    conv_t<4,4,4,0,16,false><<<dim3(196, 4, 1), T, 0, stream>>>(
        x, t_pw1, pb1, e1, 3, 224, 224, 64, 56, 56);
    // patch2: -> (16,128,28,28)                [region C free after rp4]
    conv_t<2,2,2,0,16,false><<<dim3(49, 8, 1), T, 0, stream>>>(
        e1, t_pw2, pb2, e2, 64, 56, 56, 128, 28, 28);
    // patch3: -> (16,14,14,768) NHWC           [region A free after rp2]
    conv_t<2,2,2,0,16,true><<<dim3(13, 48, 1), T, 0, stream>>>(
        e2, t_pw3, pb3, e3, 128, 28, 28, 768, 14, 14);

    // ---- ROI align + gate -> d_out (16,196,768) ----
    roi_gather<<<16 * TOPK, T, 0, stream>>>(e3, sel, gate, dout);
}